// Round 1
// baseline (368.249 us; speedup 1.0000x reference)
//
#include <hip/hip_runtime.h>
#include <math.h>

// Problem constants (fixed shapes from setup_inputs)
#define QMAXF 127.0f
#define EPSF  1e-8f
#define CIN   256
#define COUT  128
#define HW    3136        // 56*56
#define W_    56
#define NBATCH 32
#define NX4   6422528     // 32*256*3136/4
#define NPOOL 3211264     // 32*128*28*28

// ws layout (float indices)
#define WQ_OFF 64                 // wq[256]
#define BF_OFF 320                // b_fold[256]
#define CW_OFF 576                // cwq[128*256]
#define Y_OFF  33344              // y[32*128*3136]
// total floats = 33344 + 12845056 = 12878400 (~51.5 MB)

__device__ __forceinline__ float qclip(float v) {
    return fminf(fmaxf(v, -128.0f), 127.0f);
}

__device__ __forceinline__ void block_max_atomic(float v, float* red, unsigned int* dst) {
    #pragma unroll
    for (int off = 32; off > 0; off >>= 1) v = fmaxf(v, __shfl_xor(v, off));
    const int lane = threadIdx.x & 63, wid = threadIdx.x >> 6;
    if (lane == 0) red[wid] = v;
    __syncthreads();
    if (threadIdx.x == 0) {
        const int nw = blockDim.x >> 6;
        float m = red[0];
        for (int i = 1; i < nw; ++i) m = fmaxf(m, red[i]);
        atomicMax(dst, __float_as_uint(m));
    }
}

// K0: BN fold + per-channel quant of w_fold; per-row quant of conv_w; init maxima.
__global__ void k0_setup(const float* __restrict__ gamma, const float* __restrict__ beta,
                         const float* __restrict__ mean,  const float* __restrict__ var,
                         const float* __restrict__ cw,    float* __restrict__ ws) {
    __shared__ float red[4];
    const int t = threadIdx.x;
    if (blockIdx.x == COUT) {
        if (t < 4) ((unsigned int*)ws)[t] = 0u;
        // t in [0,256): one channel each
        float wf = gamma[t] / sqrtf(var[t] + 1e-5f);
        float bf = beta[t] - mean[t] * wf;
        float s  = fmaxf(fabsf(wf) / QMAXF, EPSF);
        float q  = qclip(rintf(wf / s));
        ws[WQ_OFF + t] = __fmul_rn(q, s);
        ws[BF_OFF + t] = bf;
        return;
    }
    const int o = blockIdx.x;                     // output channel row
    float w = cw[o * CIN + t];
    float v = fabsf(w);
    #pragma unroll
    for (int off = 32; off > 0; off >>= 1) v = fmaxf(v, __shfl_xor(v, off));
    if ((t & 63) == 0) red[t >> 6] = v;
    __syncthreads();
    float mx = fmaxf(fmaxf(red[0], red[1]), fmaxf(red[2], red[3]));
    float s = fmaxf(mx / QMAXF, EPSF);
    float q = qclip(rintf(w / s));
    ws[CW_OFF + o * CIN + t] = __fmul_rn(q, s);
}

// K1: global abs-max of x -> ws[0]
__global__ void k1_absmax(const float4* __restrict__ x4, unsigned int* __restrict__ wsu) {
    __shared__ float red[4];
    float m = 0.0f;
    for (int i = blockIdx.x * blockDim.x + threadIdx.x; i < NX4;
         i += gridDim.x * blockDim.x) {
        float4 v = x4[i];
        m = fmaxf(m, fmaxf(fmaxf(fabsf(v.x), fabsf(v.y)),
                           fmaxf(fabsf(v.z), fabsf(v.w))));
    }
    block_max_atomic(m, red, wsu);
}

// K2: global abs-max of BN-folded fake-quantized x -> ws[1]
__global__ void k2_absmax2(const float4* __restrict__ x4, float* __restrict__ ws) {
    __shared__ float red[4];
    const float s1 = fmaxf(ws[0] / QMAXF, EPSF);
    float m = 0.0f;
    for (int i = blockIdx.x * blockDim.x + threadIdx.x; i < NX4;
         i += gridDim.x * blockDim.x) {
        const int c = (i / 784) & (CIN - 1);      // (i*4/3136) % 256; channel const per float4
        const float wqc = ws[WQ_OFF + c];
        const float bfc = ws[BF_OFF + c];
        float4 v = x4[i];
        float vals[4] = {v.x, v.y, v.z, v.w};
        #pragma unroll
        for (int u = 0; u < 4; ++u) {
            float q1 = qclip(rintf(vals[u] / s1));
            float x2 = __fadd_rn(__fmul_rn(__fmul_rn(q1, s1), wqc), bfc);
            m = fmaxf(m, fabsf(x2));
        }
    }
    block_max_atomic(m, red, (unsigned int*)ws + 1);
}

// K3: fused-transform FP32 GEMM  y[b][o][hw] = sum_c a[b,hw,c]*cwq[o,c]; abs-max -> ws[2]
// Tile: BM=64 pixels x BN=128 (all Cout) x BK=32. 256 threads, 4x8 micro-tile each.
__global__ __launch_bounds__(256) void k3_gemm(const float* __restrict__ x,
                                               float* __restrict__ ws) {
    __shared__ float As[32][64];
    __shared__ float Bs[32][132];   // pad 132: 16B-aligned float4 rows, conflict-light
    __shared__ float Wq[CIN];
    __shared__ float Bf[CIN];
    __shared__ float red[4];

    const int t   = threadIdx.x;
    const int blk = blockIdx.x;
    const int b   = blk / 49;             // 3136/64 = 49 tiles per image, never straddles b
    const int hw0 = (blk % 49) * 64;

    const float s1 = fmaxf(ws[0] / QMAXF, EPSF);
    const float s2 = fmaxf(ws[1] / QMAXF, EPSF);

    Wq[t] = ws[WQ_OFF + t];
    Bf[t] = ws[BF_OFF + t];
    __syncthreads();

    float acc[4][8];
    #pragma unroll
    for (int i = 0; i < 4; ++i)
        #pragma unroll
        for (int j = 0; j < 8; ++j) acc[i][j] = 0.0f;

    const int tx = t & 15, ty = t >> 4;          // 16x16 thread grid
    const int am = t & 63, ak0 = (t >> 6) * 8;   // A staging: 64 pixels x 8 k each
    const int bk = t & 31, bn0 = t >> 5;         // B staging
    const float* xb = x + (size_t)b * CIN * HW + hw0 + am;

    for (int ck = 0; ck < CIN; ck += 32) {
        // Stage A with fused transform: fq(s1) -> BN fold -> fq(s2) -> ReLU
        #pragma unroll
        for (int kk = 0; kk < 8; ++kk) {
            const int k = ak0 + kk;
            const int c = ck + k;
            float xv = xb[c * HW];
            float q1 = qclip(rintf(xv / s1));
            float xd = __fmul_rn(q1, s1);
            float x2 = __fadd_rn(__fmul_rn(xd, Wq[c]), Bf[c]);
            float q2 = qclip(rintf(x2 / s2));
            As[k][am] = fmaxf(__fmul_rn(q2, s2), 0.0f);
        }
        // Stage B (quantized conv weights)
        #pragma unroll
        for (int i = 0; i < 16; ++i) {
            const int n = bn0 * 16 + i;
            Bs[bk][n] = ws[CW_OFF + n * CIN + ck + bk];
        }
        __syncthreads();
        #pragma unroll
        for (int k = 0; k < 32; ++k) {
            const float4 av = *(const float4*)&As[k][ty * 4];
            const float4 b0 = *(const float4*)&Bs[k][tx * 4];
            const float4 b1 = *(const float4*)&Bs[k][64 + tx * 4];
            const float aa[4] = {av.x, av.y, av.z, av.w};
            const float bb[8] = {b0.x, b0.y, b0.z, b0.w, b1.x, b1.y, b1.z, b1.w};
            #pragma unroll
            for (int i = 0; i < 4; ++i)
                #pragma unroll
                for (int j = 0; j < 8; ++j)
                    acc[i][j] = fmaf(aa[i], bb[j], acc[i][j]);
        }
        __syncthreads();
    }

    float mloc = 0.0f;
    #pragma unroll
    for (int i = 0; i < 4; ++i) {
        const int hw = hw0 + ty * 4 + i;
        #pragma unroll
        for (int j = 0; j < 8; ++j) {
            const int n = (j < 4) ? (4 * tx + j) : (60 + 4 * tx + j);
            const float v = acc[i][j];
            ws[Y_OFF + (size_t)(b * COUT + n) * HW + hw] = v;
            mloc = fmaxf(mloc, fabsf(v));
        }
    }
    block_max_atomic(mloc, red, (unsigned int*)ws + 2);
}

// K4: integer-domain 2x2 average pool; pooled -> d_out; abs-max -> ws[3]
__global__ void k4_pool(float* __restrict__ ws, float* __restrict__ out) {
    __shared__ float red[4];
    const float s3 = fmaxf(ws[2] / QMAXF, EPSF);
    const int idx = blockIdx.x * 256 + threadIdx.x;   // grid*256 == NPOOL exactly
    const int j   = idx % 28;
    const int tmp = idx / 28;
    const int i   = tmp % 28;
    const int bo  = tmp / 28;
    const float* yb = ws + Y_OFF + (size_t)bo * HW + (2 * i) * W_ + 2 * j;
    const float2 r0 = *(const float2*)yb;
    const float2 r1 = *(const float2*)(yb + W_);
    float q00 = qclip(rintf(r0.x / s3));
    float q01 = qclip(rintf(r0.y / s3));
    float q10 = qclip(rintf(r1.x / s3));
    float q11 = qclip(rintf(r1.y / s3));
    float p = __fmul_rn(__fmul_rn((q00 + q01) + (q10 + q11), 0.25f), s3);
    out[idx] = p;
    block_max_atomic(fabsf(p), red, (unsigned int*)ws + 3);
}

// K5: final fake-quant in place + write act_s scalar
__global__ void k5_final(float* __restrict__ out, const float* __restrict__ ws) {
    const float s4 = fmaxf(ws[3] / QMAXF, EPSF);
    const int idx = blockIdx.x * 256 + threadIdx.x;
    if (idx < NPOOL) {
        float q = qclip(rintf(out[idx] / s4));
        out[idx] = __fmul_rn(q, s4);
    } else if (idx == NPOOL) {
        out[NPOOL] = s4;
    }
}

extern "C" void kernel_launch(void* const* d_in, const int* in_sizes, int n_in,
                              void* d_out, int out_size, void* d_ws, size_t ws_size,
                              hipStream_t stream) {
    const float* x     = (const float*)d_in[0];
    const float* gamma = (const float*)d_in[1];
    const float* beta  = (const float*)d_in[2];
    const float* mean  = (const float*)d_in[3];
    const float* var   = (const float*)d_in[4];
    const float* cw    = (const float*)d_in[5];
    float* out = (float*)d_out;
    float* ws  = (float*)d_ws;

    hipLaunchKernelGGL(k0_setup, dim3(COUT + 1), dim3(256), 0, stream,
                       gamma, beta, mean, var, cw, ws);
    hipLaunchKernelGGL(k1_absmax, dim3(2048), dim3(256), 0, stream,
                       (const float4*)x, (unsigned int*)ws);
    hipLaunchKernelGGL(k2_absmax2, dim3(2048), dim3(256), 0, stream,
                       (const float4*)x, ws);
    hipLaunchKernelGGL(k3_gemm, dim3(1568), dim3(256), 0, stream, x, ws);
    hipLaunchKernelGGL(k4_pool, dim3(NPOOL / 256), dim3(256), 0, stream, ws, out);
    hipLaunchKernelGGL(k5_final, dim3((NPOOL + 256) / 256), dim3(256), 0, stream,
                       out, ws);
}

// Round 2
// 263.263 us; speedup vs baseline: 1.3988x; 1.3988x over previous
//
#include <hip/hip_runtime.h>
#include <math.h>

#define QMAXF 127.0f
#define EPSF  1e-8f
#define CIN   256
#define COUT  128
#define HW    3136        // 56*56
#define W_    56
#define NPOOL 3211264     // 32*128*28*28

typedef unsigned short u16;
typedef unsigned int   u32;
typedef __attribute__((ext_vector_type(8))) short s16x8;
typedef __attribute__((ext_vector_type(4))) float f32x4;

// ws float-index layout
#define WQ_OFF   8        // wqd[256] (f32)
#define BF_OFF   264      // b_fold[256]
#define EMAX_OFF 520      // per-channel enc(max) u32[256]
#define EMIN_OFF 776      // per-channel enc(min) u32[256]
#define CS_OFF   1032     // conv_s[128]
#define CWB_OFF  1160     // qcw as bf16 u16[128*256] = 16384 float slots
#define Y_OFF    17544    // y[32*128*3136] f32
// total = 17544 + 12845056 floats = 51.45 MB

__device__ __forceinline__ float qclip(float v) {
    return fminf(fmaxf(v, -128.0f), 127.0f);
}
// exact f32->bf16 for values exactly representable (small ints): truncate
__device__ __forceinline__ u16 bf16bits(float f) {
    return (u16)(__float_as_uint(f) >> 16);
}
// monotone float<->uint encoding (for signed atomic min/max)
__device__ __forceinline__ u32 encf(float f) {
    u32 u = __float_as_uint(f);
    return (u & 0x80000000u) ? ~u : (u | 0x80000000u);
}
__device__ __forceinline__ float decf(u32 k) {
    return __uint_as_float((k & 0x80000000u) ? (k ^ 0x80000000u) : ~k);
}

__device__ __forceinline__ void block_max_atomic(float v, float* red, u32* dst) {
    #pragma unroll
    for (int off = 32; off > 0; off >>= 1) v = fmaxf(v, __shfl_xor(v, off));
    const int lane = threadIdx.x & 63, wid = threadIdx.x >> 6;
    if (lane == 0) red[wid] = v;
    __syncthreads();
    if (threadIdx.x == 0) {
        const int nw = blockDim.x >> 6;
        float m = red[0];
        for (int i = 1; i < nw; ++i) m = fmaxf(m, red[i]);
        atomicMax(dst, __float_as_uint(m));
    }
}

// K0w: per-row quant of conv_w -> bf16 ints + conv_s; extra block inits enc arrays
__global__ void k0w(const float* __restrict__ cw, float* __restrict__ ws) {
    const int t = threadIdx.x;
    if (blockIdx.x == COUT) {
        ((u32*)ws)[EMAX_OFF + t] = 0u;
        ((u32*)ws)[EMIN_OFF + t] = 0xFFFFFFFFu;
        if (t < 2) ((u32*)ws)[2 + t] = 0u;   // y-max, pool-max atomics
        return;
    }
    __shared__ float red[4];
    const int o = blockIdx.x;
    const float wv = cw[o * CIN + t];
    float v = fabsf(wv);
    #pragma unroll
    for (int off = 32; off > 0; off >>= 1) v = fmaxf(v, __shfl_xor(v, off));
    if ((t & 63) == 0) red[t >> 6] = v;
    __syncthreads();
    const float mx = fmaxf(fmaxf(red[0], red[1]), fmaxf(red[2], red[3]));
    const float s = fmaxf(mx / QMAXF, EPSF);
    const float q = qclip(rintf(wv / s));
    ((u16*)(ws + CWB_OFF))[o * CIN + t] = bf16bits(q);   // exact int in bf16
    if (t == 0) ws[CS_OFF + o] = s;
}

// K1: per-(b,c)-row min/max of x -> per-channel enc atomics
__global__ void k1_minmax(const float* __restrict__ x, float* __restrict__ ws) {
    __shared__ float red[8];
    const int row = blockIdx.x;                       // 32*256 rows
    const float4* xr = (const float4*)(x + (size_t)row * HW);
    float mx = -3.402823466e38f, mn = 3.402823466e38f;
    for (int i = threadIdx.x; i < HW / 4; i += 256) {
        const float4 v = xr[i];
        mx = fmaxf(mx, fmaxf(fmaxf(v.x, v.y), fmaxf(v.z, v.w)));
        mn = fminf(mn, fminf(fminf(v.x, v.y), fminf(v.z, v.w)));
    }
    #pragma unroll
    for (int off = 32; off > 0; off >>= 1) {
        mx = fmaxf(mx, __shfl_xor(mx, off));
        mn = fminf(mn, __shfl_xor(mn, off));
    }
    if ((threadIdx.x & 63) == 0) {
        red[threadIdx.x >> 6] = mx;
        red[4 + (threadIdx.x >> 6)] = mn;
    }
    __syncthreads();
    if (threadIdx.x == 0) {
        mx = fmaxf(fmaxf(red[0], red[1]), fmaxf(red[2], red[3]));
        mn = fminf(fminf(red[4], red[5]), fminf(red[6], red[7]));
        const int c = row & (CIN - 1);
        atomicMax((u32*)ws + EMAX_OFF + c, encf(mx));
        atomicMin((u32*)ws + EMIN_OFF + c, encf(mn));
    }
}

// K0b: s1 from channel extremes; BN fold + quant; s2 from per-channel affine endpoints
__global__ void k0b(const float* __restrict__ g, const float* __restrict__ be,
                    const float* __restrict__ mnp, const float* __restrict__ vr,
                    float* __restrict__ ws) {
    __shared__ float red[4];
    __shared__ float s1sh;
    const int t = threadIdx.x;                        // one channel each
    const float cmax = decf(((u32*)ws)[EMAX_OFF + t]);
    const float cmin = decf(((u32*)ws)[EMIN_OFF + t]);
    float v = fmaxf(fabsf(cmax), fabsf(cmin));
    #pragma unroll
    for (int off = 32; off > 0; off >>= 1) v = fmaxf(v, __shfl_xor(v, off));
    if ((t & 63) == 0) red[t >> 6] = v;
    __syncthreads();
    if (t == 0) {
        const float m1 = fmaxf(fmaxf(red[0], red[1]), fmaxf(red[2], red[3]));
        ws[0] = m1;
        s1sh = fmaxf(m1 / QMAXF, EPSF);
    }
    __syncthreads();
    const float s1 = s1sh;
    const float wf = g[t] / sqrtf(vr[t] + 1e-5f);
    const float bf = be[t] - mnp[t] * wf;
    const float sw = fmaxf(fabsf(wf) / QMAXF, EPSF);
    const float q  = qclip(rintf(wf / sw));
    const float wqd = __fmul_rn(q, sw);
    ws[WQ_OFF + t] = wqd;
    ws[BF_OFF + t] = bf;
    const float q1h = qclip(rintf(cmax / s1));
    const float q1l = qclip(rintf(cmin / s1));
    const float xh = __fadd_rn(__fmul_rn(__fmul_rn(q1h, s1), wqd), bf);
    const float xl = __fadd_rn(__fmul_rn(__fmul_rn(q1l, s1), wqd), bf);
    float m2 = fmaxf(fabsf(xh), fabsf(xl));
    __syncthreads();          // red[] reuse
    #pragma unroll
    for (int off = 32; off > 0; off >>= 1) m2 = fmaxf(m2, __shfl_xor(m2, off));
    if ((t & 63) == 0) red[t >> 6] = m2;
    __syncthreads();
    if (t == 0) ws[1] = fmaxf(fmaxf(red[0], red[1]), fmaxf(red[2], red[3]));
}

// K3: bf16-MFMA integer GEMM with fused A transform. Block: 128 cout x 64 pix, BK=64.
__global__ __launch_bounds__(256) void k3_mfma(const float* __restrict__ x,
                                               float* __restrict__ ws) {
    __shared__ __align__(16) u16 Xs[64 * 64];     // [pixel][k] swizzled
    __shared__ __align__(16) u16 Wt[128 * 64];    // [cout][k]  swizzled
    __shared__ float Wqs[CIN], Bfs[CIN], Css[COUT];
    __shared__ float red[4];

    const int t   = threadIdx.x;
    const int b   = blockIdx.x / 49;
    const int hw0 = (blockIdx.x % 49) * 64;
    const int l   = t & 63, w = t >> 6;
    const int wc  = (w >> 1) * 64;     // wave cout base
    const int wp  = (w & 1) * 32;      // wave pixel base

    const float s1 = fmaxf(ws[0] / QMAXF, EPSF);
    const float s2 = fmaxf(ws[1] / QMAXF, EPSF);

    Wqs[t] = ws[WQ_OFF + t];
    Bfs[t] = ws[BF_OFF + t];
    if (t < COUT) Css[t] = ws[CS_OFF + t];
    __syncthreads();

    f32x4 acc[4][2];
    #pragma unroll
    for (int m = 0; m < 4; ++m)
        #pragma unroll
        for (int n = 0; n < 2; ++n) acc[m][n] = (f32x4)0.0f;

    const u16* cwb = (const u16*)(ws + CWB_OFF);
    const int px0 = (t & 15) * 4;          // X stage: 4 consecutive pixels
    const int kx  = t >> 4;                // X stage: channel within group of 16

    for (int ck = 0; ck < CIN; ck += 64) {
        // ---- stage activations (fused fq->BN->fq->ReLU, exact ints to bf16)
        #pragma unroll
        for (int ps = 0; ps < 4; ++ps) {
            const int c = ck + ps * 16 + kx;
            const float4 xv = *(const float4*)(x + ((size_t)(b * CIN + c)) * HW + hw0 + px0);
            const float wqc = Wqs[c], bfc = Bfs[c];
            const int kloc = ps * 16 + kx;
            const float vv[4] = {xv.x, xv.y, xv.z, xv.w};
            #pragma unroll
            for (int u = 0; u < 4; ++u) {
                const int p = px0 + u;
                const float q1 = qclip(rintf(vv[u] / s1));
                const float xd = __fmul_rn(q1, s1);
                const float x2 = __fadd_rn(__fmul_rn(xd, wqc), bfc);
                const float q2 = qclip(rintf(x2 / s2));
                const float a  = fmaxf(q2, 0.0f);
                Xs[p * 64 + ((((kloc >> 3) + p + (p >> 3)) & 7) * 8) + (kloc & 7)] = bf16bits(a);
            }
        }
        // ---- stage weights (already bf16 ints)
        #pragma unroll
        for (int ps = 0; ps < 4; ++ps) {
            const int o  = ps * 32 + (t >> 3);
            const int kk = (t & 7) * 8;
            const s16x8 wv = *(const s16x8*)(cwb + o * CIN + ck + kk);
            *(s16x8*)&Wt[o * 64 + ((((kk >> 3) + o + (o >> 3)) & 7) * 8)] = wv;
        }
        __syncthreads();
        #pragma unroll
        for (int ks = 0; ks < 2; ++ks) {
            const int ch = ks * 4 + (l >> 4);
            s16x8 xf[2], wfr[4];
            #pragma unroll
            for (int n = 0; n < 2; ++n) {
                const int p = wp + n * 16 + (l & 15);
                xf[n] = *(const s16x8*)&Xs[p * 64 + (((ch + p + (p >> 3)) & 7) * 8)];
            }
            #pragma unroll
            for (int m = 0; m < 4; ++m) {
                const int o = wc + m * 16 + (l & 15);
                wfr[m] = *(const s16x8*)&Wt[o * 64 + (((ch + o + (o >> 3)) & 7) * 8)];
            }
            #pragma unroll
            for (int m = 0; m < 4; ++m)
                #pragma unroll
                for (int n = 0; n < 2; ++n)
                    acc[m][n] = __builtin_amdgcn_mfma_f32_16x16x32_bf16(
                                    wfr[m], xf[n], acc[m][n], 0, 0, 0);
        }
        __syncthreads();
    }

    // ---- epilogue: scale exact int sums by s2*conv_s[o]; write y; block max
    float mloc = 0.0f;
    #pragma unroll
    for (int m = 0; m < 4; ++m) {
        #pragma unroll
        for (int n = 0; n < 2; ++n) {
            const int pix = hw0 + wp + n * 16 + (l & 15);
            #pragma unroll
            for (int r = 0; r < 4; ++r) {
                const int o = wc + m * 16 + (l >> 4) * 4 + r;
                const float sc = __fmul_rn(s2, Css[o]);
                const float val = __fmul_rn(acc[m][n][r], sc);
                ws[Y_OFF + ((size_t)(b * COUT + o)) * HW + pix] = val;
                mloc = fmaxf(mloc, fabsf(val));
            }
        }
    }
    block_max_atomic(mloc, red, (u32*)ws + 2);
}

// K4: integer-domain 2x2 average pool; pooled -> d_out; abs-max -> ws[3]
__global__ void k4_pool(float* __restrict__ ws, float* __restrict__ out) {
    __shared__ float red[4];
    const float s3 = fmaxf(ws[2] / QMAXF, EPSF);
    const int idx = blockIdx.x * 256 + threadIdx.x;   // grid*256 == NPOOL
    const int j   = idx % 28;
    const int tmp = idx / 28;
    const int i   = tmp % 28;
    const int bo  = tmp / 28;
    const float* yb = ws + Y_OFF + (size_t)bo * HW + (2 * i) * W_ + 2 * j;
    const float2 r0 = *(const float2*)yb;
    const float2 r1 = *(const float2*)(yb + W_);
    const float q00 = qclip(rintf(r0.x / s3));
    const float q01 = qclip(rintf(r0.y / s3));
    const float q10 = qclip(rintf(r1.x / s3));
    const float q11 = qclip(rintf(r1.y / s3));
    const float p = __fmul_rn(__fmul_rn((q00 + q01) + (q10 + q11), 0.25f), s3);
    out[idx] = p;
    block_max_atomic(fabsf(p), red, (u32*)ws + 3);
}

// K5: final fake-quant in place + write act_s scalar
__global__ void k5_final(float* __restrict__ out, const float* __restrict__ ws) {
    const float s4 = fmaxf(ws[3] / QMAXF, EPSF);
    const int idx = blockIdx.x * 256 + threadIdx.x;
    if (idx < NPOOL) {
        const float q = qclip(rintf(out[idx] / s4));
        out[idx] = __fmul_rn(q, s4);
    } else if (idx == NPOOL) {
        out[NPOOL] = s4;
    }
}

extern "C" void kernel_launch(void* const* d_in, const int* in_sizes, int n_in,
                              void* d_out, int out_size, void* d_ws, size_t ws_size,
                              hipStream_t stream) {
    const float* x     = (const float*)d_in[0];
    const float* gamma = (const float*)d_in[1];
    const float* beta  = (const float*)d_in[2];
    const float* mean  = (const float*)d_in[3];
    const float* var   = (const float*)d_in[4];
    const float* cw    = (const float*)d_in[5];
    float* out = (float*)d_out;
    float* ws  = (float*)d_ws;

    hipLaunchKernelGGL(k0w, dim3(COUT + 1), dim3(256), 0, stream, cw, ws);
    hipLaunchKernelGGL(k1_minmax, dim3(32 * CIN), dim3(256), 0, stream, x, ws);
    hipLaunchKernelGGL(k0b, dim3(1), dim3(256), 0, stream, gamma, beta, mean, var, ws);
    hipLaunchKernelGGL(k3_mfma, dim3(1568), dim3(256), 0, stream, x, ws);
    hipLaunchKernelGGL(k4_pool, dim3(NPOOL / 256), dim3(256), 0, stream, ws, out);
    hipLaunchKernelGGL(k5_final, dim3((NPOOL + 256) / 256), dim3(256), 0, stream,
                       out, ws);
}

// Round 3
// 139.937 us; speedup vs baseline: 2.6315x; 1.8813x over previous
//
#include <hip/hip_runtime.h>
#include <math.h>

#define QMAXF 127.0f
#define EPSF  1e-8f
#define CIN   256
#define COUT  128
#define HW    3136        // 56*56
#define W_    56
#define NPOOL 3211264     // 32*128*28*28
#define POOL_BLOCKS 1792

typedef unsigned short u16;
typedef unsigned int   u32;
typedef __attribute__((ext_vector_type(8))) short s16x8;
typedef __attribute__((ext_vector_type(4))) float f32x4;

// ws float-index layout
#define WQ_OFF   8        // wqd[256] (f32)
#define BF_OFF   264      // b_fold[256]
#define EMAX_OFF 520      // per-channel enc(max) u32[256]
#define EMIN_OFF 776      // per-channel enc(min) u32[256]
#define CS_OFF   1032     // conv_s[128]
#define CWB_OFF  1160     // qcw as bf16 u16[128*256] = 16384 float slots
#define Y_OFF    17544    // y[32*128*3136] f32
// total = 17544 + 12845056 floats = 51.45 MB

__device__ __forceinline__ float qclip(float v) {
    return fminf(fmaxf(v, -128.0f), 127.0f);
}
// exact f32->bf16 for values exactly representable (small ints): truncate
__device__ __forceinline__ u16 bf16bits(float f) {
    return (u16)(__float_as_uint(f) >> 16);
}
// monotone float<->uint encoding (for signed atomic min/max)
__device__ __forceinline__ u32 encf(float f) {
    u32 u = __float_as_uint(f);
    return (u & 0x80000000u) ? ~u : (u | 0x80000000u);
}
__device__ __forceinline__ float decf(u32 k) {
    return __uint_as_float((k & 0x80000000u) ? (k ^ 0x80000000u) : ~k);
}

__device__ __forceinline__ void block_max_atomic(float v, float* red, u32* dst) {
    #pragma unroll
    for (int off = 32; off > 0; off >>= 1) v = fmaxf(v, __shfl_xor(v, off));
    const int lane = threadIdx.x & 63, wid = threadIdx.x >> 6;
    if (lane == 0) red[wid] = v;
    __syncthreads();
    if (threadIdx.x == 0) {
        const int nw = blockDim.x >> 6;
        float m = red[0];
        for (int i = 1; i < nw; ++i) m = fmaxf(m, red[i]);
        atomicMax(dst, __float_as_uint(m));
    }
}

// K0w: per-row quant of conv_w -> bf16 ints + conv_s; extra block inits enc arrays
__global__ void k0w(const float* __restrict__ cw, float* __restrict__ ws) {
    const int t = threadIdx.x;
    if (blockIdx.x == COUT) {
        ((u32*)ws)[EMAX_OFF + t] = 0u;
        ((u32*)ws)[EMIN_OFF + t] = 0xFFFFFFFFu;
        if (t < 2) ((u32*)ws)[2 + t] = 0u;   // y-max, pool-max atomics
        return;
    }
    __shared__ float red[4];
    const int o = blockIdx.x;
    const float wv = cw[o * CIN + t];
    float v = fabsf(wv);
    #pragma unroll
    for (int off = 32; off > 0; off >>= 1) v = fmaxf(v, __shfl_xor(v, off));
    if ((t & 63) == 0) red[t >> 6] = v;
    __syncthreads();
    const float mx = fmaxf(fmaxf(red[0], red[1]), fmaxf(red[2], red[3]));
    const float s = fmaxf(mx / QMAXF, EPSF);
    const float q = qclip(rintf(wv / s));
    ((u16*)(ws + CWB_OFF))[o * CIN + t] = bf16bits(q);   // exact int in bf16
    if (t == 0) ws[CS_OFF + o] = s;
}

// K1: per-(b,c)-row min/max of x -> per-channel enc atomics
__global__ void k1_minmax(const float* __restrict__ x, float* __restrict__ ws) {
    __shared__ float red[8];
    const int row = blockIdx.x;                       // 32*256 rows
    const float4* xr = (const float4*)(x + (size_t)row * HW);
    float mx = -3.402823466e38f, mn = 3.402823466e38f;
    for (int i = threadIdx.x; i < HW / 4; i += 256) {
        const float4 v = xr[i];
        mx = fmaxf(mx, fmaxf(fmaxf(v.x, v.y), fmaxf(v.z, v.w)));
        mn = fminf(mn, fminf(fminf(v.x, v.y), fminf(v.z, v.w)));
    }
    #pragma unroll
    for (int off = 32; off > 0; off >>= 1) {
        mx = fmaxf(mx, __shfl_xor(mx, off));
        mn = fminf(mn, __shfl_xor(mn, off));
    }
    if ((threadIdx.x & 63) == 0) {
        red[threadIdx.x >> 6] = mx;
        red[4 + (threadIdx.x >> 6)] = mn;
    }
    __syncthreads();
    if (threadIdx.x == 0) {
        mx = fmaxf(fmaxf(red[0], red[1]), fmaxf(red[2], red[3]));
        mn = fminf(fminf(red[4], red[5]), fminf(red[6], red[7]));
        const int c = row & (CIN - 1);
        atomicMax((u32*)ws + EMAX_OFF + c, encf(mx));
        atomicMin((u32*)ws + EMIN_OFF + c, encf(mn));
    }
}

// K0b: s1 from channel extremes; BN fold + quant; s2 from per-channel affine endpoints
__global__ void k0b(const float* __restrict__ g, const float* __restrict__ be,
                    const float* __restrict__ mnp, const float* __restrict__ vr,
                    float* __restrict__ ws) {
    __shared__ float red[4];
    __shared__ float s1sh;
    const int t = threadIdx.x;                        // one channel each
    const float cmax = decf(((u32*)ws)[EMAX_OFF + t]);
    const float cmin = decf(((u32*)ws)[EMIN_OFF + t]);
    float v = fmaxf(fabsf(cmax), fabsf(cmin));
    #pragma unroll
    for (int off = 32; off > 0; off >>= 1) v = fmaxf(v, __shfl_xor(v, off));
    if ((t & 63) == 0) red[t >> 6] = v;
    __syncthreads();
    if (t == 0) {
        const float m1 = fmaxf(fmaxf(red[0], red[1]), fmaxf(red[2], red[3]));
        ws[0] = m1;
        s1sh = fmaxf(m1 / QMAXF, EPSF);
    }
    __syncthreads();
    const float s1 = s1sh;
    const float wf = g[t] / sqrtf(vr[t] + 1e-5f);
    const float bf = be[t] - mnp[t] * wf;
    const float sw = fmaxf(fabsf(wf) / QMAXF, EPSF);
    const float q  = qclip(rintf(wf / sw));
    const float wqd = __fmul_rn(q, sw);
    ws[WQ_OFF + t] = wqd;
    ws[BF_OFF + t] = bf;
    const float q1h = qclip(rintf(cmax / s1));
    const float q1l = qclip(rintf(cmin / s1));
    const float xh = __fadd_rn(__fmul_rn(__fmul_rn(q1h, s1), wqd), bf);
    const float xl = __fadd_rn(__fmul_rn(__fmul_rn(q1l, s1), wqd), bf);
    float m2 = fmaxf(fabsf(xh), fabsf(xl));
    __syncthreads();          // red[] reuse
    #pragma unroll
    for (int off = 32; off > 0; off >>= 1) m2 = fmaxf(m2, __shfl_xor(m2, off));
    if ((t & 63) == 0) red[t >> 6] = m2;
    __syncthreads();
    if (t == 0) ws[1] = fmaxf(fmaxf(red[0], red[1]), fmaxf(red[2], red[3]));
}

// K3: bf16-MFMA integer GEMM with fused A transform. Block: 128 cout x 64 pix, BK=64.
__global__ __launch_bounds__(256) void k3_mfma(const float* __restrict__ x,
                                               float* __restrict__ ws) {
    __shared__ __align__(16) u16 Xs[64 * 64];     // [pixel][k] swizzled
    __shared__ __align__(16) u16 Wt[128 * 64];    // [cout][k]  swizzled
    __shared__ float Wqs[CIN], Bfs[CIN], Css[COUT];
    __shared__ float red[4];

    const int t   = threadIdx.x;
    const int b   = blockIdx.x / 49;
    const int hw0 = (blockIdx.x % 49) * 64;
    const int l   = t & 63, w = t >> 6;
    const int wc  = (w >> 1) * 64;     // wave cout base
    const int wp  = (w & 1) * 32;      // wave pixel base

    const float s1 = fmaxf(ws[0] / QMAXF, EPSF);
    const float s2 = fmaxf(ws[1] / QMAXF, EPSF);

    Wqs[t] = ws[WQ_OFF + t];
    Bfs[t] = ws[BF_OFF + t];
    if (t < COUT) Css[t] = ws[CS_OFF + t];
    __syncthreads();

    f32x4 acc[4][2];
    #pragma unroll
    for (int m = 0; m < 4; ++m)
        #pragma unroll
        for (int n = 0; n < 2; ++n) acc[m][n] = (f32x4)0.0f;

    const u16* cwb = (const u16*)(ws + CWB_OFF);
    const int px0 = (t & 15) * 4;          // X stage: 4 consecutive pixels
    const int kx  = t >> 4;                // X stage: channel within group of 16

    for (int ck = 0; ck < CIN; ck += 64) {
        // ---- stage activations (fused fq->BN->fq->ReLU, exact ints to bf16)
        #pragma unroll
        for (int ps = 0; ps < 4; ++ps) {
            const int c = ck + ps * 16 + kx;
            const float4 xv = *(const float4*)(x + ((size_t)(b * CIN + c)) * HW + hw0 + px0);
            const float wqc = Wqs[c], bfc = Bfs[c];
            const int kloc = ps * 16 + kx;
            const float vv[4] = {xv.x, xv.y, xv.z, xv.w};
            #pragma unroll
            for (int u = 0; u < 4; ++u) {
                const int p = px0 + u;
                const float q1 = qclip(rintf(vv[u] / s1));
                const float xd = __fmul_rn(q1, s1);
                const float x2 = __fadd_rn(__fmul_rn(xd, wqc), bfc);
                const float q2 = qclip(rintf(x2 / s2));
                const float a  = fmaxf(q2, 0.0f);
                Xs[p * 64 + ((((kloc >> 3) + p + (p >> 3)) & 7) * 8) + (kloc & 7)] = bf16bits(a);
            }
        }
        // ---- stage weights (already bf16 ints)
        #pragma unroll
        for (int ps = 0; ps < 4; ++ps) {
            const int o  = ps * 32 + (t >> 3);
            const int kk = (t & 7) * 8;
            const s16x8 wv = *(const s16x8*)(cwb + o * CIN + ck + kk);
            *(s16x8*)&Wt[o * 64 + ((((kk >> 3) + o + (o >> 3)) & 7) * 8)] = wv;
        }
        __syncthreads();
        #pragma unroll
        for (int ks = 0; ks < 2; ++ks) {
            const int ch = ks * 4 + (l >> 4);
            s16x8 xf[2], wfr[4];
            #pragma unroll
            for (int n = 0; n < 2; ++n) {
                const int p = wp + n * 16 + (l & 15);
                xf[n] = *(const s16x8*)&Xs[p * 64 + (((ch + p + (p >> 3)) & 7) * 8)];
            }
            #pragma unroll
            for (int m = 0; m < 4; ++m) {
                const int o = wc + m * 16 + (l & 15);
                wfr[m] = *(const s16x8*)&Wt[o * 64 + (((ch + o + (o >> 3)) & 7) * 8)];
            }
            #pragma unroll
            for (int m = 0; m < 4; ++m)
                #pragma unroll
                for (int n = 0; n < 2; ++n)
                    acc[m][n] = __builtin_amdgcn_mfma_f32_16x16x32_bf16(
                                    wfr[m], xf[n], acc[m][n], 0, 0, 0);
        }
        __syncthreads();
    }

    // ---- epilogue: scale exact int sums by s2*conv_s[o]; write y; block max
    float mloc = 0.0f;
    #pragma unroll
    for (int m = 0; m < 4; ++m) {
        #pragma unroll
        for (int n = 0; n < 2; ++n) {
            const int pix = hw0 + wp + n * 16 + (l & 15);
            #pragma unroll
            for (int r = 0; r < 4; ++r) {
                const int o = wc + m * 16 + (l >> 4) * 4 + r;
                const float sc = __fmul_rn(s2, Css[o]);
                const float val = __fmul_rn(acc[m][n][r], sc);
                ws[Y_OFF + ((size_t)(b * COUT + o)) * HW + pix] = val;
                mloc = fmaxf(mloc, fabsf(val));
            }
        }
    }
    block_max_atomic(mloc, red, (u32*)ws + 2);
}

// K4: integer-domain 2x2 average pool (grid-stride, 2 outputs/thread);
// pooled -> d_out; abs-max -> ws[3]. Few blocks => few same-address atomics.
__global__ void k4_pool(float* __restrict__ ws, float* __restrict__ out) {
    __shared__ float red[4];
    const float s3 = fmaxf(ws[2] / QMAXF, EPSF);
    float mloc = 0.0f;
    const int nq2 = NPOOL / 2;                       // pairs of adjacent outputs
    for (int p = blockIdx.x * 256 + threadIdx.x; p < nq2;
         p += POOL_BLOCKS * 256) {
        const int j2  = p % 14;                      // output col pair
        const int tmp = p / 14;
        const int i   = tmp % 28;                    // output row
        const int bo  = tmp / 28;
        const float* yb = ws + Y_OFF + (size_t)bo * HW + (2 * i) * W_ + 4 * j2;
        const float4 r0 = *(const float4*)yb;
        const float4 r1 = *(const float4*)(yb + W_);
        const float q00 = qclip(rintf(r0.x / s3)), q01 = qclip(rintf(r0.y / s3));
        const float q02 = qclip(rintf(r0.z / s3)), q03 = qclip(rintf(r0.w / s3));
        const float q10 = qclip(rintf(r1.x / s3)), q11 = qclip(rintf(r1.y / s3));
        const float q12 = qclip(rintf(r1.z / s3)), q13 = qclip(rintf(r1.w / s3));
        const float p0 = __fmul_rn(__fmul_rn((q00 + q01) + (q10 + q11), 0.25f), s3);
        const float p1 = __fmul_rn(__fmul_rn((q02 + q03) + (q12 + q13), 0.25f), s3);
        float2 pv; pv.x = p0; pv.y = p1;
        *(float2*)(out + (size_t)bo * 784 + i * 28 + 2 * j2) = pv;
        mloc = fmaxf(mloc, fmaxf(fabsf(p0), fabsf(p1)));
    }
    block_max_atomic(mloc, red, (u32*)ws + 3);
}

// K5: final fake-quant in place (float4 grid-stride) + write act_s scalar
__global__ void k5_final(float* __restrict__ out, const float* __restrict__ ws) {
    const float s4 = fmaxf(ws[3] / QMAXF, EPSF);
    const int n4 = NPOOL / 4;
    for (int i = blockIdx.x * 256 + threadIdx.x; i < n4; i += 3136 * 256) {
        float4 v = *(float4*)(out + 4 * (size_t)i);
        v.x = __fmul_rn(qclip(rintf(v.x / s4)), s4);
        v.y = __fmul_rn(qclip(rintf(v.y / s4)), s4);
        v.z = __fmul_rn(qclip(rintf(v.z / s4)), s4);
        v.w = __fmul_rn(qclip(rintf(v.w / s4)), s4);
        *(float4*)(out + 4 * (size_t)i) = v;
    }
    if (blockIdx.x == 0 && threadIdx.x == 0) out[NPOOL] = s4;
}

extern "C" void kernel_launch(void* const* d_in, const int* in_sizes, int n_in,
                              void* d_out, int out_size, void* d_ws, size_t ws_size,
                              hipStream_t stream) {
    const float* x     = (const float*)d_in[0];
    const float* gamma = (const float*)d_in[1];
    const float* beta  = (const float*)d_in[2];
    const float* mean  = (const float*)d_in[3];
    const float* var   = (const float*)d_in[4];
    const float* cw    = (const float*)d_in[5];
    float* out = (float*)d_out;
    float* ws  = (float*)d_ws;

    hipLaunchKernelGGL(k0w, dim3(COUT + 1), dim3(256), 0, stream, cw, ws);
    hipLaunchKernelGGL(k1_minmax, dim3(32 * CIN), dim3(256), 0, stream, x, ws);
    hipLaunchKernelGGL(k0b, dim3(1), dim3(256), 0, stream, gamma, beta, mean, var, ws);
    hipLaunchKernelGGL(k3_mfma, dim3(1568), dim3(256), 0, stream, x, ws);
    hipLaunchKernelGGL(k4_pool, dim3(POOL_BLOCKS), dim3(256), 0, stream, ws, out);
    hipLaunchKernelGGL(k5_final, dim3(3136), dim3(256), 0, stream, out, ws);
}

// Round 4
// 127.419 us; speedup vs baseline: 2.8901x; 1.0982x over previous
//
#include <hip/hip_runtime.h>
#include <math.h>

#define QMAXF 127.0f
#define EPSF  1e-8f
#define CIN   256
#define COUT  128
#define HW    3136        // 56*56
#define W_    56
#define NPOOL 3211264     // 32*128*28*28
#define POOL_BLOCKS 1792

typedef unsigned short u16;
typedef unsigned int   u32;
typedef __attribute__((ext_vector_type(8))) short s16x8;
typedef __attribute__((ext_vector_type(4))) float f32x4;

// ws float-index layout
#define WQ_OFF   8        // wqd[256] (f32)
#define BF_OFF   264      // b_fold[256]
#define EMAX_OFF 520      // per-channel enc(max) u32[256]
#define EMIN_OFF 776      // per-channel enc(min) u32[256]
#define CS_OFF   1032     // conv_s[128]
#define CWB_OFF  1160     // qcw as bf16 u16[128*256] = 16384 float slots
#define Y_OFF    17544    // y[32*128*3136] f32

__device__ __forceinline__ float qclip(float v) {
    return fminf(fmaxf(v, -128.0f), 127.0f);
}
__device__ __forceinline__ u16 bf16bits(float f) {
    return (u16)(__float_as_uint(f) >> 16);   // exact for small ints
}
__device__ __forceinline__ u32 encf(float f) {
    u32 u = __float_as_uint(f);
    return (u & 0x80000000u) ? ~u : (u | 0x80000000u);
}
__device__ __forceinline__ float decf(u32 k) {
    return __uint_as_float((k & 0x80000000u) ? (k ^ 0x80000000u) : ~k);
}

__device__ __forceinline__ void block_max_atomic(float v, float* red, u32* dst) {
    #pragma unroll
    for (int off = 32; off > 0; off >>= 1) v = fmaxf(v, __shfl_xor(v, off));
    const int lane = threadIdx.x & 63, wid = threadIdx.x >> 6;
    if (lane == 0) red[wid] = v;
    __syncthreads();
    if (threadIdx.x == 0) {
        const int nw = blockDim.x >> 6;
        float m = red[0];
        for (int i = 1; i < nw; ++i) m = fmaxf(m, red[i]);
        atomicMax(dst, __float_as_uint(m));
    }
}

// fused per-element transform: fq(s1) -> BN fold -> fq(s2) -> ReLU (exact int result)
__device__ __forceinline__ float xform(float xv, float s1, float s2,
                                       float wqc, float bfc) {
    const float q1 = qclip(rintf(xv / s1));
    const float xd = __fmul_rn(q1, s1);
    const float x2 = __fadd_rn(__fmul_rn(xd, wqc), bfc);
    const float q2 = qclip(rintf(x2 / s2));
    return fmaxf(q2, 0.0f);
}

// K0w: per-row quant of conv_w -> bf16 ints + conv_s; extra block inits enc arrays
__global__ void k0w(const float* __restrict__ cw, float* __restrict__ ws) {
    const int t = threadIdx.x;
    if (blockIdx.x == COUT) {
        ((u32*)ws)[EMAX_OFF + t] = 0u;
        ((u32*)ws)[EMIN_OFF + t] = 0xFFFFFFFFu;
        if (t < 2) ((u32*)ws)[2 + t] = 0u;   // y-max, pool-max atomics
        return;
    }
    __shared__ float red[4];
    const int o = blockIdx.x;
    const float wv = cw[o * CIN + t];
    float v = fabsf(wv);
    #pragma unroll
    for (int off = 32; off > 0; off >>= 1) v = fmaxf(v, __shfl_xor(v, off));
    if ((t & 63) == 0) red[t >> 6] = v;
    __syncthreads();
    const float mx = fmaxf(fmaxf(red[0], red[1]), fmaxf(red[2], red[3]));
    const float s = fmaxf(mx / QMAXF, EPSF);
    const float q = qclip(rintf(wv / s));
    ((u16*)(ws + CWB_OFF))[o * CIN + t] = bf16bits(q);
    if (t == 0) ws[CS_OFF + o] = s;
}

// K1: per-(b,c)-row min/max of x -> per-channel enc atomics
__global__ void k1_minmax(const float* __restrict__ x, float* __restrict__ ws) {
    __shared__ float red[8];
    const int row = blockIdx.x;                       // 32*256 rows
    const float4* xr = (const float4*)(x + (size_t)row * HW);
    float mx = -3.402823466e38f, mn = 3.402823466e38f;
    for (int i = threadIdx.x; i < HW / 4; i += 256) {
        const float4 v = xr[i];
        mx = fmaxf(mx, fmaxf(fmaxf(v.x, v.y), fmaxf(v.z, v.w)));
        mn = fminf(mn, fminf(fminf(v.x, v.y), fminf(v.z, v.w)));
    }
    #pragma unroll
    for (int off = 32; off > 0; off >>= 1) {
        mx = fmaxf(mx, __shfl_xor(mx, off));
        mn = fminf(mn, __shfl_xor(mn, off));
    }
    if ((threadIdx.x & 63) == 0) {
        red[threadIdx.x >> 6] = mx;
        red[4 + (threadIdx.x >> 6)] = mn;
    }
    __syncthreads();
    if (threadIdx.x == 0) {
        mx = fmaxf(fmaxf(red[0], red[1]), fmaxf(red[2], red[3]));
        mn = fminf(fminf(red[4], red[5]), fminf(red[6], red[7]));
        const int c = row & (CIN - 1);
        atomicMax((u32*)ws + EMAX_OFF + c, encf(mx));
        atomicMin((u32*)ws + EMIN_OFF + c, encf(mn));
    }
}

// K0b: s1 from channel extremes; BN fold + quant; s2 from per-channel affine endpoints
__global__ void k0b(const float* __restrict__ g, const float* __restrict__ be,
                    const float* __restrict__ mnp, const float* __restrict__ vr,
                    float* __restrict__ ws) {
    __shared__ float red[4];
    __shared__ float s1sh;
    const int t = threadIdx.x;
    const float cmax = decf(((u32*)ws)[EMAX_OFF + t]);
    const float cmin = decf(((u32*)ws)[EMIN_OFF + t]);
    float v = fmaxf(fabsf(cmax), fabsf(cmin));
    #pragma unroll
    for (int off = 32; off > 0; off >>= 1) v = fmaxf(v, __shfl_xor(v, off));
    if ((t & 63) == 0) red[t >> 6] = v;
    __syncthreads();
    if (t == 0) {
        const float m1 = fmaxf(fmaxf(red[0], red[1]), fmaxf(red[2], red[3]));
        ws[0] = m1;
        s1sh = fmaxf(m1 / QMAXF, EPSF);
    }
    __syncthreads();
    const float s1 = s1sh;
    const float wf = g[t] / sqrtf(vr[t] + 1e-5f);
    const float bf = be[t] - mnp[t] * wf;
    const float sw = fmaxf(fabsf(wf) / QMAXF, EPSF);
    const float q  = qclip(rintf(wf / sw));
    const float wqd = __fmul_rn(q, sw);
    ws[WQ_OFF + t] = wqd;
    ws[BF_OFF + t] = bf;
    const float q1h = qclip(rintf(cmax / s1));
    const float q1l = qclip(rintf(cmin / s1));
    const float xh = __fadd_rn(__fmul_rn(__fmul_rn(q1h, s1), wqd), bf);
    const float xl = __fadd_rn(__fmul_rn(__fmul_rn(q1l, s1), wqd), bf);
    float m2 = fmaxf(fabsf(xh), fabsf(xl));
    __syncthreads();
    #pragma unroll
    for (int off = 32; off > 0; off >>= 1) m2 = fmaxf(m2, __shfl_xor(m2, off));
    if ((t & 63) == 0) red[t >> 6] = m2;
    __syncthreads();
    if (t == 0) ws[1] = fmaxf(fmaxf(red[0], red[1]), fmaxf(red[2], red[3]));
}

// transform + store one double-buffered tile (X: 64p x 64k; W: 128o x 64k)
__device__ __forceinline__ void stage_store(u16* __restrict__ Xb, u16* __restrict__ Wb,
                                            const float* __restrict__ xr,
                                            const s16x8* __restrict__ wreg,
                                            int t, int ck, float s1, float s2,
                                            const float* __restrict__ Wqs,
                                            const float* __restrict__ Bfs) {
    const int p = t & 63, kh = t >> 6;
    u32 pk[8];
    #pragma unroll
    for (int j = 0; j < 8; ++j) {
        const int c0 = ck + kh * 16 + 2 * j;
        const float a0 = xform(xr[2 * j],     s1, s2, Wqs[c0],     Bfs[c0]);
        const float a1 = xform(xr[2 * j + 1], s1, s2, Wqs[c0 + 1], Bfs[c0 + 1]);
        pk[j] = (__float_as_uint(a0) >> 16) | (__float_as_uint(a1) & 0xFFFF0000u);
    }
    const int g0 = kh * 2;
    uint4 v0; v0.x = pk[0]; v0.y = pk[1]; v0.z = pk[2]; v0.w = pk[3];
    uint4 v1; v1.x = pk[4]; v1.y = pk[5]; v1.z = pk[6]; v1.w = pk[7];
    *(uint4*)&Xb[p * 64 + (((g0 + p + (p >> 3)) & 7) * 8)]     = v0;
    *(uint4*)&Xb[p * 64 + (((g0 + 1 + p + (p >> 3)) & 7) * 8)] = v1;
    #pragma unroll
    for (int ps = 0; ps < 4; ++ps) {
        const int o = ps * 32 + (t >> 3);
        *(s16x8*)&Wb[o * 64 + ((((t & 7) + o + (o >> 3)) & 7) * 8)] = wreg[ps];
    }
}

// K3: bf16-MFMA integer GEMM, double-buffered LDS + register prefetch pipeline.
__global__ __launch_bounds__(256) void k3_mfma(const float* __restrict__ x,
                                               float* __restrict__ ws) {
    __shared__ __align__(16) u16 Xs[2][64 * 64];
    __shared__ __align__(16) u16 Wt[2][128 * 64];
    __shared__ float Wqs[CIN], Bfs[CIN], Css[COUT];
    __shared__ float red[4];

    const int t   = threadIdx.x;
    const int b   = blockIdx.x / 49;
    const int hw0 = (blockIdx.x % 49) * 64;
    const int l   = t & 63, w = t >> 6;
    const int wc  = (w >> 1) * 64;     // wave cout base
    const int wp  = (w & 1) * 32;      // wave pixel base

    const float s1 = fmaxf(ws[0] / QMAXF, EPSF);
    const float s2 = fmaxf(ws[1] / QMAXF, EPSF);

    Wqs[t] = ws[WQ_OFF + t];
    Bfs[t] = ws[BF_OFF + t];
    if (t < COUT) Css[t] = ws[CS_OFF + t];

    const u16* cwb = (const u16*)(ws + CWB_OFF);
    const int p  = t & 63;        // X staging pixel
    const int kh = t >> 6;        // X staging 16-k group
    const float* xb = x + (size_t)b * CIN * HW + hw0 + p;

    float xr[16];
    s16x8 wreg[4];

    // ---- prologue: prefetch tile 0
    #pragma unroll
    for (int ps = 0; ps < 4; ++ps)
        wreg[ps] = *(const s16x8*)(cwb + (ps * 32 + (t >> 3)) * CIN + (t & 7) * 8);
    #pragma unroll
    for (int j = 0; j < 16; ++j)
        xr[j] = xb[(kh * 16 + j) * HW];

    f32x4 acc[4][2];
    #pragma unroll
    for (int m = 0; m < 4; ++m)
        #pragma unroll
        for (int n = 0; n < 2; ++n) acc[m][n] = (f32x4)0.0f;

    __syncthreads();                      // Wqs/Bfs visible
    stage_store(Xs[0], Wt[0], xr, wreg, t, 0, s1, s2, Wqs, Bfs);
    __syncthreads();

    // ---- pipelined K loop: 4 tiles of BK=64
    #pragma unroll
    for (int it = 0; it < 4; ++it) {
        const int ckn = (it + 1) * 64;
        if (it < 3) {
            #pragma unroll
            for (int ps = 0; ps < 4; ++ps)
                wreg[ps] = *(const s16x8*)(cwb + (ps * 32 + (t >> 3)) * CIN + ckn + (t & 7) * 8);
            #pragma unroll
            for (int j = 0; j < 16; ++j)
                xr[j] = xb[(ckn + kh * 16 + j) * HW];
        }
        const u16* Xb = Xs[it & 1];
        const u16* Wb = Wt[it & 1];
        #pragma unroll
        for (int ks = 0; ks < 2; ++ks) {
            const int ch = ks * 4 + (l >> 4);
            s16x8 xf[2], wfr[4];
            #pragma unroll
            for (int n = 0; n < 2; ++n) {
                const int pp = wp + n * 16 + (l & 15);
                xf[n] = *(const s16x8*)&Xb[pp * 64 + (((ch + pp + (pp >> 3)) & 7) * 8)];
            }
            #pragma unroll
            for (int m = 0; m < 4; ++m) {
                const int o = wc + m * 16 + (l & 15);
                wfr[m] = *(const s16x8*)&Wb[o * 64 + (((ch + o + (o >> 3)) & 7) * 8)];
            }
            #pragma unroll
            for (int m = 0; m < 4; ++m)
                #pragma unroll
                for (int n = 0; n < 2; ++n)
                    acc[m][n] = __builtin_amdgcn_mfma_f32_16x16x32_bf16(
                                    wfr[m], xf[n], acc[m][n], 0, 0, 0);
        }
        if (it < 3)
            stage_store(Xs[(it + 1) & 1], Wt[(it + 1) & 1], xr, wreg, t, ckn,
                        s1, s2, Wqs, Bfs);
        __syncthreads();
    }

    // ---- epilogue: scale exact int sums by s2*conv_s[o]; write y; block max
    float mloc = 0.0f;
    #pragma unroll
    for (int m = 0; m < 4; ++m) {
        #pragma unroll
        for (int n = 0; n < 2; ++n) {
            const int pix = hw0 + wp + n * 16 + (l & 15);
            #pragma unroll
            for (int r = 0; r < 4; ++r) {
                const int o = wc + m * 16 + (l >> 4) * 4 + r;
                const float sc = __fmul_rn(s2, Css[o]);
                const float val = __fmul_rn(acc[m][n][r], sc);
                ws[Y_OFF + ((size_t)(b * COUT + o)) * HW + pix] = val;
                mloc = fmaxf(mloc, fabsf(val));
            }
        }
    }
    block_max_atomic(mloc, red, (u32*)ws + 2);
}

// K4: integer-domain 2x2 average pool (grid-stride); pooled -> d_out; abs-max -> ws[3]
__global__ void k4_pool(float* __restrict__ ws, float* __restrict__ out) {
    __shared__ float red[4];
    const float s3 = fmaxf(ws[2] / QMAXF, EPSF);
    float mloc = 0.0f;
    const int nq2 = NPOOL / 2;
    for (int pp = blockIdx.x * 256 + threadIdx.x; pp < nq2;
         pp += POOL_BLOCKS * 256) {
        const int j2  = pp % 14;
        const int tmp = pp / 14;
        const int i   = tmp % 28;
        const int bo  = tmp / 28;
        const float* yb = ws + Y_OFF + (size_t)bo * HW + (2 * i) * W_ + 4 * j2;
        const float4 r0 = *(const float4*)yb;
        const float4 r1 = *(const float4*)(yb + W_);
        const float q00 = qclip(rintf(r0.x / s3)), q01 = qclip(rintf(r0.y / s3));
        const float q02 = qclip(rintf(r0.z / s3)), q03 = qclip(rintf(r0.w / s3));
        const float q10 = qclip(rintf(r1.x / s3)), q11 = qclip(rintf(r1.y / s3));
        const float q12 = qclip(rintf(r1.z / s3)), q13 = qclip(rintf(r1.w / s3));
        const float p0 = __fmul_rn(__fmul_rn((q00 + q01) + (q10 + q11), 0.25f), s3);
        const float p1 = __fmul_rn(__fmul_rn((q02 + q03) + (q12 + q13), 0.25f), s3);
        float2 pv; pv.x = p0; pv.y = p1;
        *(float2*)(out + (size_t)bo * 784 + i * 28 + 2 * j2) = pv;
        mloc = fmaxf(mloc, fmaxf(fabsf(p0), fabsf(p1)));
    }
    block_max_atomic(mloc, red, (u32*)ws + 3);
}

// K5: final fake-quant in place (float4 grid-stride) + write act_s scalar
__global__ void k5_final(float* __restrict__ out, const float* __restrict__ ws) {
    const float s4 = fmaxf(ws[3] / QMAXF, EPSF);
    const int n4 = NPOOL / 4;
    for (int i = blockIdx.x * 256 + threadIdx.x; i < n4; i += 3136 * 256) {
        float4 v = *(float4*)(out + 4 * (size_t)i);
        v.x = __fmul_rn(qclip(rintf(v.x / s4)), s4);
        v.y = __fmul_rn(qclip(rintf(v.y / s4)), s4);
        v.z = __fmul_rn(qclip(rintf(v.z / s4)), s4);
        v.w = __fmul_rn(qclip(rintf(v.w / s4)), s4);
        *(float4*)(out + 4 * (size_t)i) = v;
    }
    if (blockIdx.x == 0 && threadIdx.x == 0) out[NPOOL] = s4;
}

extern "C" void kernel_launch(void* const* d_in, const int* in_sizes, int n_in,
                              void* d_out, int out_size, void* d_ws, size_t ws_size,
                              hipStream_t stream) {
    const float* x     = (const float*)d_in[0];
    const float* gamma = (const float*)d_in[1];
    const float* beta  = (const float*)d_in[2];
    const float* mean  = (const float*)d_in[3];
    const float* var   = (const float*)d_in[4];
    const float* cw    = (const float*)d_in[5];
    float* out = (float*)d_out;
    float* ws  = (float*)d_ws;

    hipLaunchKernelGGL(k0w, dim3(COUT + 1), dim3(256), 0, stream, cw, ws);
    hipLaunchKernelGGL(k1_minmax, dim3(32 * CIN), dim3(256), 0, stream, x, ws);
    hipLaunchKernelGGL(k0b, dim3(1), dim3(256), 0, stream, gamma, beta, mean, var, ws);
    hipLaunchKernelGGL(k3_mfma, dim3(1568), dim3(256), 0, stream, x, ws);
    hipLaunchKernelGGL(k4_pool, dim3(POOL_BLOCKS), dim3(256), 0, stream, ws, out);
    hipLaunchKernelGGL(k5_final, dim3(3136), dim3(256), 0, stream, out, ws);
}

// Round 5
// 119.355 us; speedup vs baseline: 3.0853x; 1.0676x over previous
//
#include <hip/hip_runtime.h>
#include <math.h>

#define QMAXF 127.0f
#define EPSF  1e-8f
#define CIN   256
#define COUT  128
#define HW    3136        // 56*56
#define W_    56
#define NPOOL 3211264     // 32*128*28*28
#define POOL_BLOCKS 1792

typedef unsigned short u16;
typedef unsigned int   u32;
typedef __attribute__((ext_vector_type(8))) short s16x8;
typedef __attribute__((ext_vector_type(4))) float f32x4;

// ws float-index layout
#define WQ_OFF   8        // wqd[256] (f32)
#define BF_OFF   264      // b_fold[256]
#define EMAX_OFF 520      // per-channel enc(max) u32[256]
#define EMIN_OFF 776      // per-channel enc(min) u32[256]
#define CS_OFF   1032     // conv_s[128]
#define CSS2_OFF 1160     // s2*conv_s[128]
#define CWB_OFF  1288     // qcw as bf16 u16[128*256] = 16384 float slots
#define LUT_OFF  17672    // u16[256*256]: c,q1+127 -> bf16(relu(q2)) = 32768 floats
#define Y_OFF    50440    // y[32*128*3136] f32  (~51.6 MB total)

__device__ __forceinline__ float qclip(float v) {
    return fminf(fmaxf(v, -128.0f), 127.0f);
}
__device__ __forceinline__ u16 bf16bits(float f) {
    return (u16)(__float_as_uint(f) >> 16);   // exact for small ints
}
__device__ __forceinline__ u32 encf(float f) {
    u32 u = __float_as_uint(f);
    return (u & 0x80000000u) ? ~u : (u | 0x80000000u);
}
__device__ __forceinline__ float decf(u32 k) {
    return __uint_as_float((k & 0x80000000u) ? (k ^ 0x80000000u) : ~k);
}

__device__ __forceinline__ void block_max_atomic(float v, float* red, u32* dst) {
    #pragma unroll
    for (int off = 32; off > 0; off >>= 1) v = fmaxf(v, __shfl_xor(v, off));
    const int lane = threadIdx.x & 63, wid = threadIdx.x >> 6;
    if (lane == 0) red[wid] = v;
    __syncthreads();
    if (threadIdx.x == 0) {
        const int nw = blockDim.x >> 6;
        float m = red[0];
        for (int i = 1; i < nw; ++i) m = fmaxf(m, red[i]);
        atomicMax(dst, __float_as_uint(m));
    }
}

// K0w: per-row quant of conv_w -> bf16 ints + conv_s; extra block inits enc arrays
__global__ void k0w(const float* __restrict__ cw, float* __restrict__ ws) {
    const int t = threadIdx.x;
    if (blockIdx.x == COUT) {
        ((u32*)ws)[EMAX_OFF + t] = 0u;
        ((u32*)ws)[EMIN_OFF + t] = 0xFFFFFFFFu;
        if (t < 2) ((u32*)ws)[2 + t] = 0u;   // y-max, pool-max atomics
        return;
    }
    __shared__ float red[4];
    const int o = blockIdx.x;
    const float wv = cw[o * CIN + t];
    float v = fabsf(wv);
    #pragma unroll
    for (int off = 32; off > 0; off >>= 1) v = fmaxf(v, __shfl_xor(v, off));
    if ((t & 63) == 0) red[t >> 6] = v;
    __syncthreads();
    const float mx = fmaxf(fmaxf(red[0], red[1]), fmaxf(red[2], red[3]));
    const float s = fmaxf(mx / QMAXF, EPSF);
    const float q = qclip(rintf(wv / s));
    ((u16*)(ws + CWB_OFF))[o * CIN + t] = bf16bits(q);
    if (t == 0) ws[CS_OFF + o] = s;
}

// K1: per-(b,c)-row min/max of x -> per-channel enc atomics
__global__ void k1_minmax(const float* __restrict__ x, float* __restrict__ ws) {
    __shared__ float red[8];
    const int row = blockIdx.x;                       // 32*256 rows
    const float4* xr = (const float4*)(x + (size_t)row * HW);
    float mx = -3.402823466e38f, mn = 3.402823466e38f;
    for (int i = threadIdx.x; i < HW / 4; i += 256) {
        const float4 v = xr[i];
        mx = fmaxf(mx, fmaxf(fmaxf(v.x, v.y), fmaxf(v.z, v.w)));
        mn = fminf(mn, fminf(fminf(v.x, v.y), fminf(v.z, v.w)));
    }
    #pragma unroll
    for (int off = 32; off > 0; off >>= 1) {
        mx = fmaxf(mx, __shfl_xor(mx, off));
        mn = fminf(mn, __shfl_xor(mn, off));
    }
    if ((threadIdx.x & 63) == 0) {
        red[threadIdx.x >> 6] = mx;
        red[4 + (threadIdx.x >> 6)] = mn;
    }
    __syncthreads();
    if (threadIdx.x == 0) {
        mx = fmaxf(fmaxf(red[0], red[1]), fmaxf(red[2], red[3]));
        mn = fminf(fminf(red[4], red[5]), fminf(red[6], red[7]));
        const int c = row & (CIN - 1);
        atomicMax((u32*)ws + EMAX_OFF + c, encf(mx));
        atomicMin((u32*)ws + EMIN_OFF + c, encf(mn));
    }
}

// K0b: s1 from channel extremes; BN fold + quant; s2 from per-channel affine endpoints
__global__ void k0b(const float* __restrict__ g, const float* __restrict__ be,
                    const float* __restrict__ mnp, const float* __restrict__ vr,
                    float* __restrict__ ws) {
    __shared__ float red[4];
    __shared__ float s1sh;
    const int t = threadIdx.x;
    const float cmax = decf(((u32*)ws)[EMAX_OFF + t]);
    const float cmin = decf(((u32*)ws)[EMIN_OFF + t]);
    float v = fmaxf(fabsf(cmax), fabsf(cmin));
    #pragma unroll
    for (int off = 32; off > 0; off >>= 1) v = fmaxf(v, __shfl_xor(v, off));
    if ((t & 63) == 0) red[t >> 6] = v;
    __syncthreads();
    if (t == 0) {
        const float m1 = fmaxf(fmaxf(red[0], red[1]), fmaxf(red[2], red[3]));
        ws[0] = m1;
        s1sh = fmaxf(m1 / QMAXF, EPSF);
    }
    __syncthreads();
    const float s1 = s1sh;
    const float wf = g[t] / sqrtf(vr[t] + 1e-5f);
    const float bf = be[t] - mnp[t] * wf;
    const float sw = fmaxf(fabsf(wf) / QMAXF, EPSF);
    const float q  = qclip(rintf(wf / sw));
    const float wqd = __fmul_rn(q, sw);
    ws[WQ_OFF + t] = wqd;
    ws[BF_OFF + t] = bf;
    const float q1h = qclip(rintf(cmax / s1));
    const float q1l = qclip(rintf(cmin / s1));
    const float xh = __fadd_rn(__fmul_rn(__fmul_rn(q1h, s1), wqd), bf);
    const float xl = __fadd_rn(__fmul_rn(__fmul_rn(q1l, s1), wqd), bf);
    float m2 = fmaxf(fabsf(xh), fabsf(xl));
    __syncthreads();
    #pragma unroll
    for (int off = 32; off > 0; off >>= 1) m2 = fmaxf(m2, __shfl_xor(m2, off));
    if ((t & 63) == 0) red[t >> 6] = m2;
    __syncthreads();
    if (t == 0) ws[1] = fmaxf(fmaxf(red[0], red[1]), fmaxf(red[2], red[3]));
}

// K0L: exact LUT for stage-2 quant: lut[c][q1+127] = bf16(relu(clip(rint(
//      ((q1*s1)*wqd_c + bf_c)/s2 )))). Also CSS2[o] = s2*conv_s[o].
__global__ void k0L(float* __restrict__ ws) {
    const int c = blockIdx.x;
    const int t = threadIdx.x;                 // q1+127 in [0,255]; 255 unused
    const float s1 = fmaxf(ws[0] / QMAXF, EPSF);
    const float s2 = fmaxf(ws[1] / QMAXF, EPSF);
    const float wqd = ws[WQ_OFF + c];
    const float bf  = ws[BF_OFF + c];
    const float q1f = (float)(t - 127);
    const float xd  = __fmul_rn(q1f, s1);
    const float x2  = __fadd_rn(__fmul_rn(xd, wqd), bf);
    const float q2  = qclip(rintf(x2 / s2));
    const float a   = fmaxf(q2, 0.0f);
    ((u16*)(ws + LUT_OFF))[(c << 8) + t] = bf16bits(a);
    if (c == 0 && t < COUT)
        ws[CSS2_OFF + t] = __fmul_rn(s2, ws[CS_OFF + t]);
}

// stage one tile (X: 32p x 64k via LUT; W: 128o x 64k from regs)
__device__ __forceinline__ void stage32(u16* __restrict__ Xs, u16* __restrict__ Wt,
                                        const float* __restrict__ xr,
                                        const s16x8* __restrict__ wreg,
                                        int t, int ck, float s1,
                                        const u16* __restrict__ lut) {
    const int p = t & 31, kh = t >> 5;
    u32 pk[4];
    #pragma unroll
    for (int jj = 0; jj < 4; ++jj) {
        const int c0 = ck + kh * 8 + 2 * jj;
        const float q1a = rintf(xr[2 * jj] / s1);        // |x/s1| <= 127+ulp: no clip
        const float q1b = rintf(xr[2 * jj + 1] / s1);
        const u32 lo = lut[(c0 << 8) + 127 + (int)q1a];
        const u32 hi = lut[((c0 + 1) << 8) + 127 + (int)q1b];
        pk[jj] = lo | (hi << 16);
    }
    uint4 v; v.x = pk[0]; v.y = pk[1]; v.z = pk[2]; v.w = pk[3];
    *(uint4*)&Xs[p * 64 + (((kh + p + (p >> 3)) & 7) * 8)] = v;
    #pragma unroll
    for (int ps = 0; ps < 4; ++ps) {
        const int o = ps * 32 + (t >> 3);
        *(s16x8*)&Wt[o * 64 + ((((t & 7) + o + (o >> 3)) & 7) * 8)] = wreg[ps];
    }
}

// K3: bf16-MFMA integer GEMM, 32-pixel tiles (3136 blocks), single-buffer LDS,
// register prefetch of next K-tile, LUT-based activation transform.
__global__ __launch_bounds__(256) void k3_mfma(const float* __restrict__ x,
                                               float* __restrict__ ws) {
    __shared__ __align__(16) u16 Xs[32 * 64];
    __shared__ __align__(16) u16 Wt[128 * 64];
    __shared__ float Css2s[COUT];
    __shared__ float red[4];

    const int t   = threadIdx.x;
    const int b   = blockIdx.x / 98;
    const int hw0 = (blockIdx.x % 98) * 32;
    const int l   = t & 63, w = t >> 6;
    const int wc  = w * 32;                    // wave cout base (4 waves x 32)

    const float s1 = fmaxf(ws[0] / QMAXF, EPSF);
    const u16* lut = (const u16*)(ws + LUT_OFF);
    const u16* cwb = (const u16*)(ws + CWB_OFF);

    if (t < COUT) Css2s[t] = ws[CSS2_OFF + t];

    const int p  = t & 31;        // staging pixel
    const int kh = t >> 5;        // staging 8-k group
    const float* xb = x + (size_t)b * CIN * HW + hw0 + p;

    float xr[8];
    s16x8 wreg[4];

    // prologue: prefetch + stage tile 0
    #pragma unroll
    for (int ps = 0; ps < 4; ++ps)
        wreg[ps] = *(const s16x8*)(cwb + (ps * 32 + (t >> 3)) * CIN + (t & 7) * 8);
    #pragma unroll
    for (int j = 0; j < 8; ++j)
        xr[j] = xb[(kh * 8 + j) * HW];

    f32x4 acc[2][2];
    #pragma unroll
    for (int m = 0; m < 2; ++m)
        #pragma unroll
        for (int n = 0; n < 2; ++n) acc[m][n] = (f32x4)0.0f;

    stage32(Xs, Wt, xr, wreg, t, 0, s1, lut);
    __syncthreads();

    #pragma unroll
    for (int it = 0; it < 4; ++it) {
        const int ckn = (it + 1) * 64;
        if (it < 3) {       // prefetch next K-tile into regs (overlaps MFMA)
            #pragma unroll
            for (int ps = 0; ps < 4; ++ps)
                wreg[ps] = *(const s16x8*)(cwb + (ps * 32 + (t >> 3)) * CIN + ckn + (t & 7) * 8);
            #pragma unroll
            for (int j = 0; j < 8; ++j)
                xr[j] = xb[(ckn + kh * 8 + j) * HW];
        }
        #pragma unroll
        for (int ks = 0; ks < 2; ++ks) {
            const int ch = ks * 4 + (l >> 4);
            s16x8 xf[2], wfr[2];
            #pragma unroll
            for (int n = 0; n < 2; ++n) {
                const int pp = n * 16 + (l & 15);
                xf[n] = *(const s16x8*)&Xs[pp * 64 + (((ch + pp + (pp >> 3)) & 7) * 8)];
            }
            #pragma unroll
            for (int m = 0; m < 2; ++m) {
                const int o = wc + m * 16 + (l & 15);
                wfr[m] = *(const s16x8*)&Wt[o * 64 + (((ch + o + (o >> 3)) & 7) * 8)];
            }
            #pragma unroll
            for (int m = 0; m < 2; ++m)
                #pragma unroll
                for (int n = 0; n < 2; ++n)
                    acc[m][n] = __builtin_amdgcn_mfma_f32_16x16x32_bf16(
                                    wfr[m], xf[n], acc[m][n], 0, 0, 0);
        }
        if (it < 3) {
            __syncthreads();
            stage32(Xs, Wt, xr, wreg, t, ckn, s1, lut);
            __syncthreads();
        }
    }

    // epilogue: scale exact int sums; write y; block max
    float mloc = 0.0f;
    #pragma unroll
    for (int m = 0; m < 2; ++m) {
        #pragma unroll
        for (int n = 0; n < 2; ++n) {
            const int pix = hw0 + n * 16 + (l & 15);
            #pragma unroll
            for (int r = 0; r < 4; ++r) {
                const int o = wc + m * 16 + (l >> 4) * 4 + r;
                const float val = __fmul_rn(acc[m][n][r], Css2s[o]);
                ws[Y_OFF + ((size_t)(b * COUT + o)) * HW + pix] = val;
                mloc = fmaxf(mloc, fabsf(val));
            }
        }
    }
    block_max_atomic(mloc, red, (u32*)ws + 2);
}

// K4: integer-domain 2x2 average pool (grid-stride); pooled -> d_out; abs-max -> ws[3]
__global__ void k4_pool(float* __restrict__ ws, float* __restrict__ out) {
    __shared__ float red[4];
    const float s3 = fmaxf(ws[2] / QMAXF, EPSF);
    float mloc = 0.0f;
    const int nq2 = NPOOL / 2;
    for (int pp = blockIdx.x * 256 + threadIdx.x; pp < nq2;
         pp += POOL_BLOCKS * 256) {
        const int j2  = pp % 14;
        const int tmp = pp / 14;
        const int i   = tmp % 28;
        const int bo  = tmp / 28;
        const float* yb = ws + Y_OFF + (size_t)bo * HW + (2 * i) * W_ + 4 * j2;
        const float4 r0 = *(const float4*)yb;
        const float4 r1 = *(const float4*)(yb + W_);
        const float q00 = qclip(rintf(r0.x / s3)), q01 = qclip(rintf(r0.y / s3));
        const float q02 = qclip(rintf(r0.z / s3)), q03 = qclip(rintf(r0.w / s3));
        const float q10 = qclip(rintf(r1.x / s3)), q11 = qclip(rintf(r1.y / s3));
        const float q12 = qclip(rintf(r1.z / s3)), q13 = qclip(rintf(r1.w / s3));
        const float p0 = __fmul_rn(__fmul_rn((q00 + q01) + (q10 + q11), 0.25f), s3);
        const float p1 = __fmul_rn(__fmul_rn((q02 + q03) + (q12 + q13), 0.25f), s3);
        float2 pv; pv.x = p0; pv.y = p1;
        *(float2*)(out + (size_t)bo * 784 + i * 28 + 2 * j2) = pv;
        mloc = fmaxf(mloc, fmaxf(fabsf(p0), fabsf(p1)));
    }
    block_max_atomic(mloc, red, (u32*)ws + 3);
}

// K5: final fake-quant in place (float4 grid-stride) + write act_s scalar
__global__ void k5_final(float* __restrict__ out, const float* __restrict__ ws) {
    const float s4 = fmaxf(ws[3] / QMAXF, EPSF);
    const int n4 = NPOOL / 4;
    for (int i = blockIdx.x * 256 + threadIdx.x; i < n4; i += 3136 * 256) {
        float4 v = *(float4*)(out + 4 * (size_t)i);
        v.x = __fmul_rn(qclip(rintf(v.x / s4)), s4);
        v.y = __fmul_rn(qclip(rintf(v.y / s4)), s4);
        v.z = __fmul_rn(qclip(rintf(v.z / s4)), s4);
        v.w = __fmul_rn(qclip(rintf(v.w / s4)), s4);
        *(float4*)(out + 4 * (size_t)i) = v;
    }
    if (blockIdx.x == 0 && threadIdx.x == 0) out[NPOOL] = s4;
}

extern "C" void kernel_launch(void* const* d_in, const int* in_sizes, int n_in,
                              void* d_out, int out_size, void* d_ws, size_t ws_size,
                              hipStream_t stream) {
    const float* x     = (const float*)d_in[0];
    const float* gamma = (const float*)d_in[1];
    const float* beta  = (const float*)d_in[2];
    const float* mean  = (const float*)d_in[3];
    const float* var   = (const float*)d_in[4];
    const float* cw    = (const float*)d_in[5];
    float* out = (float*)d_out;
    float* ws  = (float*)d_ws;

    hipLaunchKernelGGL(k0w, dim3(COUT + 1), dim3(256), 0, stream, cw, ws);
    hipLaunchKernelGGL(k1_minmax, dim3(32 * CIN), dim3(256), 0, stream, x, ws);
    hipLaunchKernelGGL(k0b, dim3(1), dim3(256), 0, stream, gamma, beta, mean, var, ws);
    hipLaunchKernelGGL(k0L, dim3(256), dim3(256), 0, stream, ws);
    hipLaunchKernelGGL(k3_mfma, dim3(3136), dim3(256), 0, stream, x, ws);
    hipLaunchKernelGGL(k4_pool, dim3(POOL_BLOCKS), dim3(256), 0, stream, ws, out);
    hipLaunchKernelGGL(k5_final, dim3(3136), dim3(256), 0, stream, out, ws);
}